// Round 4
// baseline (179.128 us; speedup 1.0000x reference)
//
#include <hip/hip_runtime.h>
#include <hip/hip_bf16.h>
#include <stdint.h>

#define N1 8192
#define N2 16384
#define DIM 256
#define BM 128            // rows per block
#define BN 256            // cols per block
#define RB 64             // row-blocks (8192/128)
#define CB 64             // col-blocks (16384/256)
#define NPART CB

typedef short v8s  __attribute__((ext_vector_type(8)));   // 8 x bf16 bits
typedef float f32x4 __attribute__((ext_vector_type(4)));

#define GLD16(g, l)                                                                         \
  __builtin_amdgcn_global_load_lds((const __attribute__((address_space(1))) uint32_t*)(g),  \
                                   (__attribute__((address_space(3))) uint32_t*)(l), 16, 0, 0)

__device__ __forceinline__ void top3_insert(float v, float& t0, float& t1, float& t2) {
    float nt1 = __builtin_amdgcn_fmed3f(v, t0, t1);
    float nt2 = __builtin_amdgcn_fmed3f(v, t1, t2);
    t0 = fmaxf(t0, v);
    t1 = nt1;
    t2 = nt2;
}

// 16 lanes per row, 4 rows per wave, 16 rows per block. Each lane: 4 x float4
// loads in flight (ILP), 4-step width-16 shuffle reduce, 4 x uint2 stores.
__global__ __launch_bounds__(256) void normalize_kernel(
        const float* __restrict__ inA, const float* __restrict__ inB,
        __hip_bfloat16* __restrict__ outA, __hip_bfloat16* __restrict__ outB) {
    const int wave = threadIdx.x >> 6;
    const int lane = threadIdx.x & 63;
    const int rgrp = lane >> 4;
    const int li   = lane & 15;
    const int gr   = blockIdx.x * 16 + wave * 4 + rgrp;   // 0..24575
    const float* in;
    __hip_bfloat16* out;
    int row;
    if (gr < N1) { in = inA; out = outA; row = gr; }
    else         { in = inB; out = outB; row = gr - N1; }
    const float* rp = in + (size_t)row * DIM + li * 4;
    float4 v[4];
    #pragma unroll
    for (int j = 0; j < 4; ++j) v[j] = *(const float4*)(rp + j * 64);
    float s = 0.f;
    #pragma unroll
    for (int j = 0; j < 4; ++j)
        s += v[j].x * v[j].x + v[j].y * v[j].y + v[j].z * v[j].z + v[j].w * v[j].w;
    #pragma unroll
    for (int off = 8; off; off >>= 1) s += __shfl_xor(s, off, 64);
    const float inv = 1.0f / sqrtf(s);
    __hip_bfloat16* wp = out + (size_t)row * DIM + li * 4;
    #pragma unroll
    for (int j = 0; j < 4; ++j) {
        __hip_bfloat16 o[4];
        o[0] = __float2bfloat16(v[j].x * inv);
        o[1] = __float2bfloat16(v[j].y * inv);
        o[2] = __float2bfloat16(v[j].z * inv);
        o[3] = __float2bfloat16(v[j].w * inv);
        *(uint2*)(wp + j * 64) = *(uint2*)o;
    }
}

// Block 128x256 C-tile, 4 waves (2m x 2n), wave tile 64x128 (4rt x 8ct of 16x16).
// BK=64, single-buffered 48KB LDS -> 2 blocks/CU; the two independent blocks
// overlap each other's barrier drains (the R0 mechanism, measured to work).
// Geometry vs R0: ds_reads/MFMA 0.5 -> 0.375, so per-CU LDS-read pipe demand
// (73.7k cyc) drops BELOW the MFMA floor (79.5k) — R0/R2 were LDS-read-bound.
// One output tile per block: K=256 as 4 unrolled K-tiles, top3 fold once at end.
// R3 BUGFIX: the two wn col-half waves previously wrote the SAME partial slot
// (lost half the columns). Now merged in-block via LDS (fbuf[row][wn]) and one
// triple per (row, cb) is written; NPART stays 64.
__global__ __launch_bounds__(256, 2) void gemm_top3_kernel(
        const __hip_bfloat16* __restrict__ A, const __hip_bfloat16* __restrict__ B,
        float* __restrict__ partial) {
    __shared__ char smem[49152];    // A[128][64] 16KB @0 | B[256][64] 32KB @16384

    const int tid  = threadIdx.x;
    const int wave = tid >> 6;
    const int lane = tid & 63;
    const int lo   = lane & 15;
    const int quad = lane >> 4;
    const int wm   = wave >> 1;      // 0..1 row-half
    const int wn   = wave & 1;       // 0..1 col-half
    const int rb   = blockIdx.x & 63;   // consecutive bids: same B-panel
    const int cb   = blockIdx.x >> 6;   // readers of one A-panel all on one XCD
    const int row0 = rb * BM;
    const int col0 = cb * BN;

    // staging constants: lane covers row wave*8+(lane>>3) of each 32-row group,
    // physical slot lane&7; source chunk = slot ^ (row&7) (row&7 == lane>>3).
    const int srow8 = lane >> 3;
    const int sslot = lane & 7;
    const size_t goff = (size_t)(wave * 8 + srow8) * 512 + (size_t)((sslot ^ srow8) << 4);
    const char* Ag = (const char*)A + (size_t)row0 * 512 + goff;
    const char* Bg = (const char*)B + (size_t)col0 * 512 + goff;
    char* tileA = smem;
    char* tileB = smem + 16384;

    // ds_read offsets: row r at r*128; physical slot = (ks*4+quad) ^ (r&7)
    int aoff[2], boff[2];
    #pragma unroll
    for (int ks = 0; ks < 2; ++ks) {
        const int swz = (((ks * 4 + quad) ^ (lo & 7)) << 4);
        aoff[ks] = (wm * 64 + lo) * 128 + swz;
        boff[ks] = 16384 + (wn * 128 + lo) * 128 + swz;
    }

    f32x4 acc[4][8];

    #pragma unroll
    for (int kt = 0; kt < 4; ++kt) {
        __syncthreads();             // previous tile's ds_reads done (no-op at kt=0)
        #pragma unroll
        for (int g = 0; g < 4; ++g)
            GLD16(Ag + (size_t)g * 16384 + kt * 128, tileA + g * 4096 + wave * 1024);
        #pragma unroll
        for (int g = 0; g < 8; ++g)
            GLD16(Bg + (size_t)g * 16384 + kt * 128, tileB + g * 4096 + wave * 1024);
        __syncthreads();             // compiler emits vmcnt(0) drain before barrier
        #pragma unroll
        for (int ks = 0; ks < 2; ++ks) {
            v8s af[4];
            #pragma unroll
            for (int rt = 0; rt < 4; ++rt)
                af[rt] = *(const v8s*)(smem + aoff[ks] + rt * 2048);
            __builtin_amdgcn_s_setprio(1);
            #pragma unroll
            for (int ct = 0; ct < 8; ++ct) {
                v8s bf = *(const v8s*)(smem + boff[ks] + ct * 2048);
                #pragma unroll
                for (int rt = 0; rt < 4; ++rt) {
                    if (kt == 0 && ks == 0)
                        acc[rt][ct] = __builtin_amdgcn_mfma_f32_16x16x32_bf16(
                            af[rt], bf, (f32x4){0.f, 0.f, 0.f, 0.f}, 0, 0, 0);
                    else
                        acc[rt][ct] = __builtin_amdgcn_mfma_f32_16x16x32_bf16(
                            af[rt], bf, acc[rt][ct], 0, 0, 0);
                }
            }
            __builtin_amdgcn_s_setprio(0);
        }
    }

    // epilogue: per row-slot fold 8 ct values, merge the 16 lo-lanes (same row,
    // different cols) by shuffle, then merge the two wn col-halves via LDS.
    __syncthreads();                 // all waves done reading the tiles
    float* fbuf = (float*)smem;      // [128 rows][2 wn][3]
    #pragma unroll
    for (int rt = 0; rt < 4; ++rt) {
        #pragma unroll
        for (int r = 0; r < 4; ++r) {
            float u0 = -1e30f, u1 = -1e30f, u2 = -1e30f;
            #pragma unroll
            for (int ct = 0; ct < 8; ++ct)
                top3_insert(acc[rt][ct][r], u0, u1, u2);
            #pragma unroll
            for (int step = 1; step < 16; step <<= 1) {
                float b0 = __shfl_xor(u0, step, 64);
                float b1 = __shfl_xor(u1, step, 64);
                float b2 = __shfl_xor(u2, step, 64);
                top3_insert(b0, u0, u1, u2);
                top3_insert(b1, u0, u1, u2);
                top3_insert(b2, u0, u1, u2);
            }
            if (lo == 0) {
                const int row = wm * 64 + rt * 16 + quad * 4 + r;
                float* p = fbuf + (row * 2 + wn) * 3;
                p[0] = u0; p[1] = u1; p[2] = u2;
            }
        }
    }
    __syncthreads();
    if (tid < BM) {
        const float* p = fbuf + tid * 6;
        float u0 = p[0], u1 = p[1], u2 = p[2];
        top3_insert(p[3], u0, u1, u2);
        top3_insert(p[4], u0, u1, u2);
        top3_insert(p[5], u0, u1, u2);
        float* o = partial + ((size_t)(row0 + tid) * NPART + cb) * 3;
        o[0] = u0; o[1] = u1; o[2] = u2;
    }
}

// 4 threads per row, 12 float4 loads each, 2-step quad shuffle merge.
__global__ __launch_bounds__(256) void merge_kernel(
        const float* __restrict__ partial, float* __restrict__ out) {
    const int row = blockIdx.x * 64 + (threadIdx.x >> 2);
    const int sub = threadIdx.x & 3;
    const float4* p = (const float4*)(partial + (size_t)row * NPART * 3) + sub * 12;
    float t0 = -1e30f, t1 = -1e30f, t2 = -1e30f;
    #pragma unroll
    for (int i = 0; i < 12; ++i) {
        float4 v = p[i];
        top3_insert(v.x, t0, t1, t2);
        top3_insert(v.y, t0, t1, t2);
        top3_insert(v.z, t0, t1, t2);
        top3_insert(v.w, t0, t1, t2);
    }
    #pragma unroll
    for (int step = 1; step < 4; step <<= 1) {
        float b0 = __shfl_xor(t0, step, 64);
        float b1 = __shfl_xor(t1, step, 64);
        float b2 = __shfl_xor(t2, step, 64);
        top3_insert(b0, t0, t1, t2);
        top3_insert(b1, t0, t1, t2);
        top3_insert(b2, t0, t1, t2);
    }
    if (sub == 0) out[row] = (t0 + t1 + t2) * (1.0f / 3.0f);
}

extern "C" void kernel_launch(void* const* d_in, const int* in_sizes, int n_in,
                              void* d_out, int out_size, void* d_ws, size_t ws_size,
                              hipStream_t stream) {
    const float* tA = (const float*)d_in[0];
    const float* tB = (const float*)d_in[1];
    float* out = (float*)d_out;

    __hip_bfloat16* An = (__hip_bfloat16*)d_ws;
    __hip_bfloat16* Bn = An + (size_t)N1 * DIM;
    float* partial = (float*)(Bn + (size_t)N2 * DIM);

    normalize_kernel<<<(N1 + N2) / 16, 256, 0, stream>>>(tA, tB, An, Bn);
    gemm_top3_kernel<<<RB * CB, 256, 0, stream>>>(An, Bn, partial);
    merge_kernel<<<N1 / 64, 256, 0, stream>>>(partial, out);
}

// Round 5
// 139.647 us; speedup vs baseline: 1.2827x; 1.2827x over previous
//
#include <hip/hip_runtime.h>
#include <hip/hip_bf16.h>
#include <stdint.h>

#define N1 8192
#define N2 16384
#define DIM 256
#define BM 256              // rows per block = 8 waves x 32
#define CS 8                // col-splits (== 8 XCDs)
#define COLS (N2 / CS)      // 2048 cols per block
#define TC 64               // cols per tile
#define NT (COLS / TC)      // 32 tiles per block
#define NPART CS

typedef short v8s  __attribute__((ext_vector_type(8)));   // 8 x bf16 bits
typedef float f32x4 __attribute__((ext_vector_type(4)));

#define GLD16(g, l)                                                                         \
  __builtin_amdgcn_global_load_lds((const __attribute__((address_space(1))) uint32_t*)(g),  \
                                   (__attribute__((address_space(3))) uint32_t*)(l), 16, 0, 0)

__device__ __forceinline__ void top3_insert(float v, float& t0, float& t1, float& t2) {
    float nt1 = __builtin_amdgcn_fmed3f(v, t0, t1);
    float nt2 = __builtin_amdgcn_fmed3f(v, t1, t2);
    t0 = fmaxf(t0, v);
    t1 = nt1;
    t2 = nt2;
}

// 16 lanes per row, 4 rows per wave, 16 rows per block. Each lane: 4 x float4
// loads in flight (ILP), 4-step width-16 shuffle reduce, 4 x uint2 stores.
__global__ __launch_bounds__(256) void normalize_kernel(
        const float* __restrict__ inA, const float* __restrict__ inB,
        __hip_bfloat16* __restrict__ outA, __hip_bfloat16* __restrict__ outB) {
    const int wave = threadIdx.x >> 6;
    const int lane = threadIdx.x & 63;
    const int rgrp = lane >> 4;
    const int li   = lane & 15;
    const int gr   = blockIdx.x * 16 + wave * 4 + rgrp;   // 0..24575
    const float* in;
    __hip_bfloat16* out;
    int row;
    if (gr < N1) { in = inA; out = outA; row = gr; }
    else         { in = inB; out = outB; row = gr - N1; }
    const float* rp = in + (size_t)row * DIM + li * 4;
    float4 v[4];
    #pragma unroll
    for (int j = 0; j < 4; ++j) v[j] = *(const float4*)(rp + j * 64);
    float s = 0.f;
    #pragma unroll
    for (int j = 0; j < 4; ++j)
        s += v[j].x * v[j].x + v[j].y * v[j].y + v[j].z * v[j].z + v[j].w * v[j].w;
    #pragma unroll
    for (int off = 8; off; off >>= 1) s += __shfl_xor(s, off, 64);
    const float inv = 1.0f / sqrtf(s);
    __hip_bfloat16* wp = out + (size_t)row * DIM + li * 4;
    #pragma unroll
    for (int j = 0; j < 4; ++j) {
        __hip_bfloat16 o[4];
        o[0] = __float2bfloat16(v[j].x * inv);
        o[1] = __float2bfloat16(v[j].y * inv);
        o[2] = __float2bfloat16(v[j].z * inv);
        o[3] = __float2bfloat16(v[j].w * inv);
        *(uint2*)(wp + j * 64) = *(uint2*)o;
    }
}

// A-in-registers GEMM+top3. Block = 256 rows x 2048 cols; 8 waves x 32 rows.
// Each lane holds its A fragments (af[2][8], 64 VGPR) for the WHOLE kernel —
// A is loaded once from global, never staged to LDS. Only B streams through
// LDS: 64-col tiles (32KB), double-buffered, staged 2 ahead with counted
// vmcnt(4) gates (never 0 until drain) + 2 barriers/tile. This cuts staged
// L2/LLC traffic 1 GB -> 289 MB vs R0 (the measured bottleneck) and leaves
// the matrix pipe dominant per tile (128 MFMA/SIMD ~2.5k cyc vs ~32 ds_reads).
// cs = bid&7: each 1 MB B-slab is resident in exactly one XCD's L2.
// Swizzle: B col c chunk g stored at phys slot g^(c&7); any aligned 8-lane
// group reads 8 distinct bank-groups -> conflict-free (same family as R0,
// measured 0 conflicts).
__global__ __launch_bounds__(512, 2) void gemm_top3_kernel(
        const __hip_bfloat16* __restrict__ A, const __hip_bfloat16* __restrict__ B,
        float* __restrict__ partial) {
    __shared__ char smem[2 * 32768];   // B tile double buffer

    const int tid  = threadIdx.x;
    const int wave = tid >> 6;
    const int lane = tid & 63;
    const int lo   = lane & 15;
    const int quad = lane >> 4;
    const int cs   = blockIdx.x & 7;   // round-robin dispatch -> cs == XCD
    const int rb   = blockIdx.x >> 3;
    const int row0 = rb * BM;

    // ---- A fragments in registers: A[row0+wave*32+rt*16+lo][s*32+quad*8..+7] ----
    v8s af[2][8];
    {
        const char* arow = (const char*)A + (size_t)(row0 + wave * 32 + lo) * 512 + quad * 16;
        #pragma unroll
        for (int rt = 0; rt < 2; ++rt)
            #pragma unroll
            for (int s = 0; s < 8; ++s)
                af[rt][s] = *(const v8s*)(arow + rt * 8192 + s * 64);
    }
    // af loads must complete before staging so in-loop vmcnt counts are pure B.
    asm volatile("s_waitcnt vmcnt(0)" ::: "memory");

    // ---- staging constants: thread covers col j*16 + wave*2 + (lane>>5),
    // phys chunk lane&31, source logical chunk (lane&31)^(col&7) ----
    const char* Bb = (const char*)B + (size_t)cs * COLS * 512;
    int gsrc[4];
    #pragma unroll
    for (int j = 0; j < 4; ++j) {
        const int col = j * 16 + wave * 2 + (lane >> 5);
        gsrc[j] = col * 512 + (((lane & 31) ^ (col & 7)) << 4);
    }

    // ---- read-side swizzle: phys = (s*4+quad) ^ (lo&7); col base (ct*16+lo)*512 ----
    int swz[8];
    #pragma unroll
    for (int s = 0; s < 8; ++s) swz[s] = (((s * 4 + quad) ^ (lo & 7)) << 4);
    int bco[4];
    #pragma unroll
    for (int ct = 0; ct < 4; ++ct) bco[ct] = (ct * 16 + lo) * 512;

    float t0[8], t1[8], t2[8];
    #pragma unroll
    for (int i = 0; i < 8; ++i) { t0[i] = -1e30f; t1[i] = -1e30f; t2[i] = -1e30f; }

    // ---- prologue: stage tiles 0 and 1 ----
    #pragma unroll
    for (int j = 0; j < 4; ++j)
        GLD16(Bb + gsrc[j], smem + j * 8192 + wave * 1024);
    #pragma unroll
    for (int j = 0; j < 4; ++j)
        GLD16(Bb + 32768 + gsrc[j], smem + 32768 + j * 8192 + wave * 1024);

    #pragma unroll 2
    for (int t = 0; t < NT; ++t) {
        if (t == NT - 1) asm volatile("s_waitcnt vmcnt(0)" ::: "memory");
        else             asm volatile("s_waitcnt vmcnt(4)" ::: "memory");
        __builtin_amdgcn_s_barrier();    // all waves: tile t landed

        const char* bbuf = smem + (t & 1) * 32768;
        f32x4 acc[2][4];
        __builtin_amdgcn_s_setprio(1);
        #pragma unroll
        for (int s = 0; s < 8; ++s) {
            #pragma unroll
            for (int ct = 0; ct < 4; ++ct) {
                v8s bf = *(const v8s*)(bbuf + bco[ct] + swz[s]);
                #pragma unroll
                for (int rt = 0; rt < 2; ++rt) {
                    if (s == 0)
                        acc[rt][ct] = __builtin_amdgcn_mfma_f32_16x16x32_bf16(
                            af[rt][0], bf, (f32x4){0.f, 0.f, 0.f, 0.f}, 0, 0, 0);
                    else
                        acc[rt][ct] = __builtin_amdgcn_mfma_f32_16x16x32_bf16(
                            af[rt][s], bf, acc[rt][ct], 0, 0, 0);
                }
            }
        }
        __builtin_amdgcn_s_setprio(0);
        __builtin_amdgcn_s_barrier();    // all waves done reading buf[t&1]
        if (t + 2 < NT) {                // stage t+2 into the buffer just freed
            const char* src = Bb + (size_t)(t + 2) * 32768;
            char* dst = smem + (t & 1) * 32768;
            #pragma unroll
            for (int j = 0; j < 4; ++j)
                GLD16(src + gsrc[j], dst + j * 8192 + wave * 1024);
        }
        // fold this tile's 32 C-values/lane into running top3 (VALU, hides
        // under the in-flight stage)
        #pragma unroll
        for (int rt = 0; rt < 2; ++rt)
            #pragma unroll
            for (int r = 0; r < 4; ++r) {
                const int sl = rt * 4 + r;
                #pragma unroll
                for (int ct = 0; ct < 4; ++ct)
                    top3_insert(acc[rt][ct][r], t0[sl], t1[sl], t2[sl]);
            }
    }

    // merge across the 16 lo-lanes (same row, different col residues)
    #pragma unroll
    for (int sl = 0; sl < 8; ++sl) {
        #pragma unroll
        for (int step = 1; step < 16; step <<= 1) {
            float b0 = __shfl_xor(t0[sl], step, 64);
            float b1 = __shfl_xor(t1[sl], step, 64);
            float b2 = __shfl_xor(t2[sl], step, 64);
            top3_insert(b0, t0[sl], t1[sl], t2[sl]);
            top3_insert(b1, t0[sl], t1[sl], t2[sl]);
            top3_insert(b2, t0[sl], t1[sl], t2[sl]);
        }
    }
    if (lo == 0) {
        #pragma unroll
        for (int rt = 0; rt < 2; ++rt)
            #pragma unroll
            for (int r = 0; r < 4; ++r) {
                const int row = row0 + wave * 32 + rt * 16 + quad * 4 + r;
                float* p = partial + ((size_t)row * NPART + cs) * 3;
                const int sl = rt * 4 + r;
                p[0] = t0[sl]; p[1] = t1[sl]; p[2] = t2[sl];
            }
    }
}

// 1 thread per row: 6 float4 loads (24 values), 24 inserts.
__global__ __launch_bounds__(256) void merge_kernel(
        const float* __restrict__ partial, float* __restrict__ out) {
    const int row = blockIdx.x * 256 + threadIdx.x;
    if (row >= N1) return;
    const float4* p = (const float4*)(partial + (size_t)row * NPART * 3);
    float t0 = -1e30f, t1 = -1e30f, t2 = -1e30f;
    #pragma unroll
    for (int i = 0; i < 6; ++i) {
        float4 v = p[i];
        top3_insert(v.x, t0, t1, t2);
        top3_insert(v.y, t0, t1, t2);
        top3_insert(v.z, t0, t1, t2);
        top3_insert(v.w, t0, t1, t2);
    }
    out[row] = (t0 + t1 + t2) * (1.0f / 3.0f);
}

extern "C" void kernel_launch(void* const* d_in, const int* in_sizes, int n_in,
                              void* d_out, int out_size, void* d_ws, size_t ws_size,
                              hipStream_t stream) {
    const float* tA = (const float*)d_in[0];
    const float* tB = (const float*)d_in[1];
    float* out = (float*)d_out;

    __hip_bfloat16* An = (__hip_bfloat16*)d_ws;
    __hip_bfloat16* Bn = An + (size_t)N1 * DIM;
    float* partial = (float*)(Bn + (size_t)N2 * DIM);

    normalize_kernel<<<(N1 + N2) / 16, 256, 0, stream>>>(tA, tB, An, Bn);
    gemm_top3_kernel<<<(N1 / BM) * CS, 512, 0, stream>>>(An, Bn, partial);
    merge_kernel<<<(N1 + 255) / 256, 256, 0, stream>>>(partial, out);
}